// Round 23
// baseline (749.861 us; speedup 1.0000x reference)
//
#include <hip/hip_runtime.h>
#include <math.h>

#define NN 25000
#define KNB 16
#define HH 128
#define VV 32000
#define BB 50
#define LL 128
#define NTK 4
#define NGRAPH 25
#define GCH 20

typedef __attribute__((ext_vector_type(8))) short s16x8;
typedef __attribute__((ext_vector_type(4))) float f32x4;
typedef _Float16 h16x2 __attribute__((ext_vector_type(2)));

__device__ __forceinline__ float fexp2(float x) {
#if __has_builtin(__builtin_amdgcn_exp2f)
    return __builtin_amdgcn_exp2f(x);
#else
    return exp2f(x);
#endif
}
__device__ __forceinline__ float frcp(float x) {
#if __has_builtin(__builtin_amdgcn_rcpf)
    return __builtin_amdgcn_rcpf(x);
#else
    return 1.f / x;
#endif
}
__device__ __forceinline__ float fsigm(float x) { return frcp(1.f + fexp2(x * -1.4426950408889634f)); }
__device__ __forceinline__ float ftanh(float x) { return 1.f - 2.f * frcp(1.f + fexp2(x * 2.8853900817779268f)); }

__device__ __forceinline__ unsigned short f2bf(float x) {
    unsigned int u = __float_as_uint(x);
    unsigned int r = (u + 0x7fffu + ((u >> 16) & 1u)) >> 16;
    return (unsigned short)r;
}
__device__ __forceinline__ float bf2f(unsigned int b) {
    return __uint_as_float((b & 0xffffu) << 16);
}

template<int CTRL>
__device__ __forceinline__ float qxor(float x) {
#if __has_builtin(__builtin_amdgcn_mov_dpp)
    return __int_as_float(__builtin_amdgcn_mov_dpp(__float_as_int(x), CTRL, 0xf, 0xf, true));
#else
    int m = (CTRL == 0xB1) ? 1 : (CTRL == 0x4E) ? 2 : 3;
    return __shfl_xor(x, m, 64);
#endif
}

__device__ __forceinline__ float hdot(unsigned int a, unsigned int b, float c) {
#if __has_builtin(__builtin_amdgcn_fdot2)
    return __builtin_amdgcn_fdot2(__builtin_bit_cast(h16x2, a), __builtin_bit_cast(h16x2, b), c, false);
#else
    h16x2 av = __builtin_bit_cast(h16x2, a), bv = __builtin_bit_cast(h16x2, b);
    return c + (float)av[0] * (float)bv[0] + (float)av[1] * (float)bv[1];
#endif
}

// ---------------- embed f32 -> bf16 ----------------
__global__ __launch_bounds__(256) void embconv_k(const float* __restrict__ e,
                                                 unsigned short* __restrict__ o)
{
    int i = blockIdx.x * 256 + threadIdx.x;
    if (i < VV * 128) o[i] = f2bf(e[i]);
}

// ---------------- weight prep (R8 layout) ----------------
__global__ __launch_bounds__(256) void wprep_k(
    const float* __restrict__ ndWih, const float* __restrict__ ndWhh,
    const float* __restrict__ fWg0, const float* __restrict__ fWgr,
    const float* __restrict__ fWo0, const float* __restrict__ fWor,
    const float* __restrict__ bWg0, const float* __restrict__ bWgr,
    const float* __restrict__ bWo0, const float* __restrict__ bWor,
    const float* __restrict__ sfWih, const float* __restrict__ sbWih,
    const float* __restrict__ sfWhh, const float* __restrict__ sbWhh,
    unsigned short* __restrict__ dst)
{
    int idx = blockIdx.x * 256 + threadIdx.x;
    if (idx >= 1146880) return;
    if (idx >= 884736) {
        int r = idx - 884736;
        int d = r >> 17;
        int o = r & 131071;
        int pairIdx = o >> 1, hf = o & 1;
        int k2 = pairIdx >> 9, n = pairIdx & 511;
        int k = k2 * 2 + hf;
        int unit = n >> 2, gate = n & 3;
        const float* W = d ? sbWhh : sfWhh;
        _Float16 hv = (_Float16)W[(gate * 128 + unit) * 128 + k];
        dst[idx] = __builtin_bit_cast(unsigned short, hv);
        return;
    }
    float val;
    if (idx < 131072) {
        int r = idx >> 8, k = idx & 255;
        int unit = r >> 2, gate = r & 3;
        int srow = (gate << 7) + unit;
        val = (k < 128) ? ndWih[srow * 128 + k] : ndWhh[srow * 128 + (k - 128)];
    } else if (idx < 753664) {
        int r = idx - 131072;
        int dir = r / 311296;
        int o = r % 311296;
        const float* Wg0 = dir ? bWg0 : fWg0;
        const float* Wgr = dir ? bWgr : fWgr;
        const float* Wo0 = dir ? bWo0 : fWo0;
        const float* Wor = dir ? bWor : fWor;
        if (o < 16384) {
            int n = o >> 7, k = o & 127;
            val = Wg0[k * 128 + n];
        } else if (o < 147456) {
            int p = o - 16384;
            int j = p >> 16, q = p & 65535;
            int n = q >> 8, k = q & 255;
            val = Wgr[j * 65536 + k * 256 + n];
        } else if (o < 180224) {
            int p = o - 147456;
            int s = p >> 14, q = p & 16383;
            int n = q >> 7, k = q & 127;
            val = Wo0[s * 16384 + k * 128 + n];
        } else {
            int p = o - 180224;
            int js = p >> 15, q = p & 32767;
            int n = q >> 8, k = q & 255;
            val = Wor[js * 32768 + k * 128 + n];
        }
    } else if (idx < 819200) {
        val = sfWih[idx - 753664];
    } else {
        val = sbWih[idx - 819200];
    }
    dst[idx] = f2bf(val);
}

__global__ __launch_bounds__(256) void tokrev_k(const int* __restrict__ idx,
                                                const int* __restrict__ lens,
                                                int* __restrict__ tokrev)
{
    int t = blockIdx.x * 256 + threadIdx.x;
    if (t >= BB * LL) return;
    int b = t / LL, tt = t % LL;
    int r = lens[b] - 1 - tt;
    r = r < 0 ? 0 : (r > LL - 1 ? LL - 1 : r);
    tokrev[t] = idx[b * LL + r];
}

// ---------------- phase-1 dual xg GEMM ----------------
__global__ __launch_bounds__(256) void hgemm1_k(
    const unsigned short* __restrict__ embedbf,
    const int* __restrict__ gidxA, const int* __restrict__ gidxB,
    const unsigned short* __restrict__ WtA, const unsigned short* __restrict__ WtB,
    const float* __restrict__ biasA, const float* __restrict__ biasB,
    float* __restrict__ outA, float* __restrict__ outB)
{
    __shared__ unsigned short Asm[128 * 64];
    __shared__ unsigned short Bsm[128 * 64];
    const int tid = threadIdx.x;
    const int lane = tid & 63, w = tid >> 6;
    const int wm = w >> 1, wn = w & 1;
    const int lane15 = lane & 15, hi = lane >> 4;
    const int y = blockIdx.y;
    const int* gidx = (y < 4) ? gidxA : gidxB;
    const unsigned short* Wt = (y < 4) ? WtA : WtB;
    const float* bias = (y < 4) ? biasA : biasB;
    float* outp = (y < 4) ? outA : outB;
    const int bm0 = blockIdx.x * 128, bn0 = (y & 3) * 128;
    const int M = BB * LL, K = 128;
    f32x4 acc[4][4];
#pragma unroll
    for (int i = 0; i < 4; ++i)
#pragma unroll
        for (int j = 0; j < 4; ++j) acc[i][j] = (f32x4){0.f, 0.f, 0.f, 0.f};

    for (int kt = 0; kt < K; kt += 64) {
#pragma unroll
        for (int r = 0; r < 4; ++r) {
            int id = tid + r * 256;
            int row = id >> 3, cc = id & 7;
            int m = bm0 + row;
            s16x8 v = {0, 0, 0, 0, 0, 0, 0, 0};
            if (m < M) {
                int g = gidx[m];
                v = *(const s16x8*)(embedbf + (size_t)g * 128 + kt + cc * 8);
            }
            int byt = (cc * 16) ^ ((row & 7) << 4);
            *(s16x8*)((char*)Asm + row * 128 + byt) = v;
        }
#pragma unroll
        for (int r = 0; r < 4; ++r) {
            int id = tid + r * 256;
            int row = id >> 3, cc = id & 7;
            s16x8 v = *(const s16x8*)(Wt + (size_t)(bn0 + row) * K + kt + cc * 8);
            int byt = (cc * 16) ^ ((row & 7) << 4);
            *(s16x8*)((char*)Bsm + row * 128 + byt) = v;
        }
        __syncthreads();
#pragma unroll
        for (int ks = 0; ks < 2; ++ks) {
            s16x8 af[4], bf[4];
#pragma unroll
            for (int mi = 0; mi < 4; ++mi) {
                int row = wm * 64 + mi * 16 + lane15;
                int byt = (ks * 64 + (hi * 16)) ^ ((row & 7) << 4);
                af[mi] = *(const s16x8*)((char*)Asm + row * 128 + byt);
            }
#pragma unroll
            for (int ni = 0; ni < 4; ++ni) {
                int row = wn * 64 + ni * 16 + lane15;
                int byt = (ks * 64 + (hi * 16)) ^ ((row & 7) << 4);
                bf[ni] = *(const s16x8*)((char*)Bsm + row * 128 + byt);
            }
#pragma unroll
            for (int mi = 0; mi < 4; ++mi)
#pragma unroll
                for (int ni = 0; ni < 4; ++ni)
                    acc[mi][ni] = __builtin_amdgcn_mfma_f32_16x16x32_bf16(af[mi], bf[ni], acc[mi][ni], 0, 0, 0);
        }
        __syncthreads();
    }
#pragma unroll
    for (int mi = 0; mi < 4; ++mi) {
#pragma unroll
        for (int ni = 0; ni < 4; ++ni) {
            int n = bn0 + wn * 64 + ni * 16 + lane15;
#pragma unroll
            for (int j = 0; j < 4; ++j) {
                int m = bm0 + wm * 64 + mi * 16 + hi * 4 + j;
                if (m < M) {
                    float v = acc[mi][ni][j] + bias[n];
                    int nn = ((n & 127) << 2) | (n >> 7);
                    outp[(size_t)m * 512 + nn] = v;
                }
            }
        }
    }
}

// ---------------- merged node-LSTM step + seq-LSTM chunk (unchanged) ----------------
__global__ __launch_bounds__(512, 4) void node_seq_k(
    const unsigned short* __restrict__ embedbf,
    const int* __restrict__ nodefeat,
    const unsigned short* __restrict__ hrd,
    const unsigned short* __restrict__ nodeW,
    const float* __restrict__ ndb,
    unsigned short* __restrict__ hwr,
    unsigned short* __restrict__ cbuf,
    int step,
    const float* __restrict__ xgf, const float* __restrict__ xgb,
    const unsigned short* __restrict__ wseq,
    const int* __restrict__ lens,
    float* __restrict__ senc,
    unsigned short* __restrict__ hseq, float* __restrict__ cseq)
{
    __shared__ __align__(16) unsigned char smem[32768 + 512];
    const int bid = blockIdx.x;
    const int tid = threadIdx.x;

    if (bid >= 784) {
        int sid = bid - 784;
        int dir = sid >= BB ? 1 : 0;
        int b = dir ? sid - BB : sid;
        int len = lens[b];
        int t0 = step * 32;
        if (t0 >= len) return;
        int t1 = t0 + 32 < len ? t0 + 32 : len;
        const float* xg = (dir ? xgb : xgf) + (size_t)b * LL * 512;
        const unsigned int* wp = (const unsigned int*)(wseq + dir * 131072);
        int q = tid & 3, unit = tid >> 2;
        unsigned int wreg[64];
#pragma unroll
        for (int k2 = 0; k2 < 64; ++k2) wreg[k2] = wp[k2 * 512 + tid];
        unsigned short* hlsq = (unsigned short*)smem;
        float cj = 0.f;
        if (step == 0) {
            if (tid < 128) hlsq[tid] = 0;
        } else {
            if (tid < 128) hlsq[tid] = hseq[sid * 128 + tid];
            if (q == 0) cj = cseq[sid * 128 + unit];
        }
        __syncthreads();
        float xcur = xg[(size_t)t0 * 512 + tid];
        int pb = 0;
        for (int t = t0; t < t1; ++t) {
            float xnext = (t + 1 < t1) ? xg[(size_t)(t + 1) * 512 + tid] : 0.f;
            const uint4* hp = (const uint4*)&hlsq[pb * 128];
            float p0 = 0.f, p1 = 0.f, p2 = 0.f, p3 = 0.f;
#pragma unroll
            for (int i = 0; i < 4; ++i) {
                uint4 h0 = hp[i * 4 + 0], h1 = hp[i * 4 + 1], h2 = hp[i * 4 + 2], h3 = hp[i * 4 + 3];
                const unsigned int* w0 = &wreg[i * 16];
                p0 = hdot(h0.x, w0[0], p0);  p0 = hdot(h0.y, w0[1], p0);
                p0 = hdot(h0.z, w0[2], p0);  p0 = hdot(h0.w, w0[3], p0);
                p1 = hdot(h1.x, w0[4], p1);  p1 = hdot(h1.y, w0[5], p1);
                p1 = hdot(h1.z, w0[6], p1);  p1 = hdot(h1.w, w0[7], p1);
                p2 = hdot(h2.x, w0[8], p2);  p2 = hdot(h2.y, w0[9], p2);
                p2 = hdot(h2.z, w0[10], p2); p2 = hdot(h2.w, w0[11], p2);
                p3 = hdot(h3.x, w0[12], p3); p3 = hdot(h3.y, w0[13], p3);
                p3 = hdot(h3.z, w0[14], p3); p3 = hdot(h3.w, w0[15], p3);
            }
            float accv = xcur + ((p0 + p1) + (p2 + p3));
            float tv = (q == 2) ? ftanh(accv) : fsigm(accv);
            float v1 = __shfl_xor(tv, 1), v2 = __shfl_xor(tv, 2), v3 = __shfl_xor(tv, 3);
            if (q == 0) {
                cj = v1 * cj + tv * v2;
                float hv = v3 * ftanh(cj);
                _Float16 hh = (_Float16)hv;
                hlsq[(pb ^ 1) * 128 + unit] = __builtin_bit_cast(unsigned short, hh);
                int tout = dir ? (len - 1 - t) : t;
                senc[((size_t)b * LL + tout) * 256 + dir * 128 + unit] = hv;
            }
            __syncthreads();
            pb ^= 1;
            xcur = xnext;
        }
        if (q == 0) cseq[sid * 128 + unit] = cj;
        if (tid < 128) hseq[sid * 128 + tid] = hlsq[pb * 128 + tid];
        return;
    }

    unsigned short* Asm = (unsigned short*)smem;
    unsigned short* Bsm = (unsigned short*)(smem + 16384);
    const int lane = tid & 63, w = tid >> 6;
    const int wm = w & 1, wn = w >> 1;
    const int lane15 = lane & 15, hi = lane >> 4, q = lane & 3;
    const int bx = bid % 196, y = bid / 196;
    const int bm0 = bx * 128, bn0 = y * 128;
    const int czero = (step == 0);

    f32x4 acc[4][2];
#pragma unroll
    for (int i = 0; i < 4; ++i)
#pragma unroll
        for (int j = 0; j < 2; ++j) acc[i][j] = (f32x4){0.f, 0.f, 0.f, 0.f};

    for (int kt = 0; kt < 256; kt += 64) {
#pragma unroll
        for (int r = 0; r < 2; ++r) {
            int id = tid + r * 512;
            int row = id >> 3, cc = id & 7;
            int m = bm0 + row;
            s16x8 v = {0, 0, 0, 0, 0, 0, 0, 0};
            if (m < NN) {
                int k0 = kt + cc * 8;
                if (k0 < 128) {
                    int g = nodefeat[m * NTK + step];
                    v = *(const s16x8*)(embedbf + (size_t)g * 128 + k0);
                } else if (!czero) {
                    v = *(const s16x8*)(hrd + (size_t)m * 128 + (k0 - 128));
                }
            }
            int byt = (cc * 16) ^ ((row & 7) << 4);
            *(s16x8*)((char*)Asm + row * 128 + byt) = v;
        }
#pragma unroll
        for (int r = 0; r < 2; ++r) {
            int id = tid + r * 512;
            int row = id >> 3, cc = id & 7;
            s16x8 v = *(const s16x8*)(nodeW + (size_t)(bn0 + row) * 256 + kt + cc * 8);
            int byt = (cc * 16) ^ ((row & 7) << 4);
            *(s16x8*)((char*)Bsm + row * 128 + byt) = v;
        }
        __syncthreads();
#pragma unroll
        for (int ks = 0; ks < 2; ++ks) {
            s16x8 af[4], bf[2];
#pragma unroll
            for (int mi = 0; mi < 4; ++mi) {
                int row = wm * 64 + mi * 16 + lane15;
                int byt = (ks * 64 + (hi * 16)) ^ ((row & 7) << 4);
                af[mi] = *(const s16x8*)((char*)Asm + row * 128 + byt);
            }
#pragma unroll
            for (int ni = 0; ni < 2; ++ni) {
                int row = wn * 32 + ni * 16 + lane15;
                int byt = (ks * 64 + (hi * 16)) ^ ((row & 7) << 4);
                bf[ni] = *(const s16x8*)((char*)Bsm + row * 128 + byt);
            }
#pragma unroll
            for (int mi = 0; mi < 4; ++mi)
#pragma unroll
                for (int ni = 0; ni < 2; ++ni)
                    acc[mi][ni] = __builtin_amdgcn_mfma_f32_16x16x32_bf16(af[mi], bf[ni], acc[mi][ni], 0, 0, 0);
        }
        __syncthreads();
    }
    unsigned short* cb = cbuf + (((size_t)bid * 8 + w) * 64 + lane) * 8;
    float crv[8];
    if (czero) {
#pragma unroll
        for (int i = 0; i < 8; ++i) crv[i] = 0.f;
    } else {
        uint4 w0 = *(const uint4*)cb;
        unsigned int wd[4] = {w0.x, w0.y, w0.z, w0.w};
#pragma unroll
        for (int i = 0; i < 8; ++i) crv[i] = bf2f(wd[i >> 1] >> ((i & 1) * 16));
    }
    const bool qb0 = (lane & 1), qb1 = (lane & 2);
#pragma unroll
    for (int mi = 0; mi < 4; ++mi) {
#pragma unroll
        for (int ni = 0; ni < 2; ++ni) {
            int n = bn0 + wn * 32 + ni * 16 + lane15;
            int unit = n >> 2;
            float bval = ndb[((n & 3) << 7) + unit];
#pragma unroll
            for (int j = 0; j < 4; ++j) {
                float v = acc[mi][ni][j] + bval;
                float tv = (q == 2) ? ftanh(v) : fsigm(v);
                float v1 = qxor<0xB1>(tv), v2 = qxor<0x4E>(tv), v3 = qxor<0x1B>(tv);
                if (q == j) {
                    float gf = qb0 ? (qb1 ? v2 : tv) : (qb1 ? v3 : v1);
                    float gig = qb0 ? (v1 * v3) : (tv * v2);
                    float go = qb0 ? (qb1 ? tv : v2) : (qb1 ? v1 : v3);
                    float cc = gf * crv[mi * 2 + ni] + gig;
                    crv[mi * 2 + ni] = cc;
                    int m = bm0 + wm * 64 + mi * 16 + hi * 4 + j;
                    if (m < NN) hwr[(size_t)m * HH + unit] = f2bf(go * ftanh(cc));
                }
            }
        }
    }
    unsigned int wd[4];
#pragma unroll
    for (int p = 0; p < 4; ++p)
        wd[p] = (unsigned int)f2bf(crv[2 * p]) | ((unsigned int)f2bf(crv[2 * p + 1]) << 16);
    *(uint4*)cb = make_uint4(wd[0], wd[1], wd[2], wd[3]);
}

// ---------------- fused per-layer kernel: barrier-free K-loop, W direct from L2 ----------------
// grid = 784 (XCD-swizzled): work = (orig%8)*98 + orig/8; dir = work/392; mt = work%392
// LDS: As + Gs only (64KB @ D=256). W fragments read per-wave straight from global (L2-resident).
// Exactly 2 barriers: after As stage, before neigh panel reads Gs.
template<int D, int OF32OUT>
__global__ __launch_bounds__(512, 4) void layer_fused_k(
    const unsigned short* __restrict__ cur, int curds,
    const unsigned short* __restrict__ ctx, int ctxds,     // read-only aux
    const unsigned short* __restrict__ wg, int wgds,
    const float* __restrict__ bgf, const float* __restrict__ bgb,
    const unsigned short* __restrict__ wo, int wods, int wrs,
    const float* __restrict__ bof, const float* __restrict__ bob,
    void* __restrict__ outb, int outds)
{
    __shared__ unsigned short As[64 * D];
    __shared__ unsigned short Gs[64 * D];
    constexpr int gt = D / 128;
    const int tid = threadIdx.x;
    const int lane = tid & 63, w = tid >> 6;
    const int wm = w >> 1, wn = w & 1;            // 4 row-groups (16 rows) x 2 col-groups (64 cols)
    const int lane15 = lane & 15, hi = lane >> 4;
    const int orig = blockIdx.x;
    const int work = (orig & 7) * 98 + (orig >> 3);
    const int dir = work / 392;
    const int mt = work % 392;
    const int bm0 = mt * 64;
    const unsigned short* curd = cur + (size_t)dir * curds;
    const unsigned short* ctxd = ctx + (size_t)dir * ctxds;
    const float* bg = dir ? bgb : bgf;
    const float* bo = dir ? bob : bof;

    // stage cur tile into As (16-row XOR swizzle), once
    constexpr int CH = D / 8;
#pragma unroll
    for (int r = 0; r < D / 64; ++r) {
        int id = tid + r * 512;
        int row = id / CH, cc = id % CH;
        int m = bm0 + row;
        s16x8 v = {0, 0, 0, 0, 0, 0, 0, 0};
        if (m < NN) v = *(const s16x8*)(curd + (size_t)m * D + cc * 8);
        *(s16x8*)((char*)As + row * (D * 2) + ((cc * 16) ^ ((row & 15) << 4))) = v;
    }
    __syncthreads();

    // panels: gate tiles then self — barrier-free (W from global, As read-only)
#pragma unroll
    for (int p = 0; p <= gt; ++p) {
        const bool isgate = p < gt;
        const int colBase = isgate ? p * 128 : 0;
        const unsigned short* Wt = isgate ? (wg + (size_t)dir * wgds + (size_t)colBase * D)
                                          : (wo + (size_t)dir * wods);
        const unsigned short* wbase = Wt + (size_t)(wn * 64 + lane15) * D + hi * 8;
        f32x4 acc[4];
#pragma unroll
        for (int i = 0; i < 4; ++i) acc[i] = (f32x4){0.f, 0.f, 0.f, 0.f};
#pragma unroll
        for (int kt = 0; kt < D; kt += 64) {
#pragma unroll
            for (int ks = 0; ks < 2; ++ks) {
                int kk = kt + ks * 32;
                s16x8 af;
                {
                    int row = wm * 16 + lane15;
                    af = *(const s16x8*)((char*)As + row * (D * 2)
                              + (((kk + hi * 8) * 2) ^ ((row & 15) << 4)));
                }
#pragma unroll
                for (int ni = 0; ni < 4; ++ni) {
                    s16x8 bf = *(const s16x8*)(wbase + (size_t)(ni * 16) * D + kk);
                    acc[ni] = __builtin_amdgcn_mfma_f32_16x16x32_bf16(af, bf, acc[ni], 0, 0, 0);
                }
            }
        }
        // epilogue
#pragma unroll
        for (int ni = 0; ni < 4; ++ni) {
            int ncol = wn * 64 + ni * 16 + lane15;
#pragma unroll
            for (int j = 0; j < 4; ++j) {
                int rr = wm * 16 + hi * 4 + j;
                int m = bm0 + rr;
                if (isgate) {
                    int col = colBase + ncol;
                    float v = acc[ni][j] + bg[col];
                    int ma = (m < NN) ? m : 0;
                    v = fsigm(v) * bf2f(ctxd[(size_t)ma * D + col]);
                    unsigned int pv = f2bf(v);
                    unsigned int po = __shfl_xor((int)pv, 1);
                    if ((lane15 & 1) == 0) {
                        unsigned int word = pv | (po << 16);
                        *(unsigned int*)((char*)Gs + rr * (D * 2) + (((col * 2) & ~3) ^ ((rr & 15) << 4))) = word;
                    }
                } else if (m < NN) {
                    float v = fmaxf(acc[ni][j] + bo[ncol], 0.f);
                    if (OF32OUT) ((float*)outb)[(size_t)m * 512 + dir * 256 + ncol] = v;
                    else ((unsigned short*)outb)[(size_t)dir * outds + (size_t)m * 256 + ncol] = f2bf(v);
                }
            }
        }
    }
    __syncthreads();   // all Gs writes complete

    // neigh panel: A = Gs, W = wo role 1 (global)
    {
        const unsigned short* Wt = wo + (size_t)dir * wods + (size_t)wrs;
        const unsigned short* wbase = Wt + (size_t)(wn * 64 + lane15) * D + hi * 8;
        f32x4 acc[4];
#pragma unroll
        for (int i = 0; i < 4; ++i) acc[i] = (f32x4){0.f, 0.f, 0.f, 0.f};
#pragma unroll
        for (int kt = 0; kt < D; kt += 64) {
#pragma unroll
            for (int ks = 0; ks < 2; ++ks) {
                int kk = kt + ks * 32;
                s16x8 af;
                {
                    int row = wm * 16 + lane15;
                    af = *(const s16x8*)((char*)Gs + row * (D * 2)
                              + (((kk + hi * 8) * 2) ^ ((row & 15) << 4)));
                }
#pragma unroll
                for (int ni = 0; ni < 4; ++ni) {
                    s16x8 bf = *(const s16x8*)(wbase + (size_t)(ni * 16) * D + kk);
                    acc[ni] = __builtin_amdgcn_mfma_f32_16x16x32_bf16(af, bf, acc[ni], 0, 0, 0);
                }
            }
        }
#pragma unroll
        for (int ni = 0; ni < 4; ++ni) {
            int ncol = wn * 64 + ni * 16 + lane15;
#pragma unroll
            for (int j = 0; j < 4; ++j) {
                int m = bm0 + wm * 16 + hi * 4 + j;
                if (m < NN) {
                    float v = fmaxf(acc[ni][j] + bo[128 + ncol], 0.f);
                    if (OF32OUT) ((float*)outb)[(size_t)m * 512 + dir * 256 + 128 + ncol] = v;
                    else ((unsigned short*)outb)[(size_t)dir * outds + (size_t)m * 256 + 128 + ncol] = f2bf(v);
                }
            }
        }
    }
}

// ---------------- mask + zero-invalid + max_len ----------------
__global__ __launch_bounds__(256) void finalize_k(const int* __restrict__ idx,
                                                  const int* __restrict__ lens,
                                                  float* __restrict__ senc,
                                                  float* __restrict__ mask,
                                                  float* __restrict__ omax,
                                                  const int* __restrict__ mlin)
{
    int id = blockIdx.x * 256 + threadIdx.x;
    if (id == 0) omax[0] = (float)mlin[0];
    if (id >= BB * LL * 64) return;
    int row = id >> 6, c = id & 63;
    int b = row / LL, tt = row % LL;
    if (c == 0) mask[row] = (idx[row] == 0) ? 1.f : 0.f;
    if (tt >= lens[b]) *(float4*)&senc[(size_t)row * 256 + c * 4] = make_float4(0.f, 0.f, 0.f, 0.f);
}

// ---------------- es1[n] = exp(hid[n,:]·att1) precompute (dirs via grid.y) ----------------
template<int D>
__global__ __launch_bounds__(256) void sdot_k(const unsigned short* __restrict__ hidb, int hidds,
                                              const float* __restrict__ a1f, const float* __restrict__ a1b,
                                              float* __restrict__ s1)
{
    constexpr int V = D / 64;
    int dir = blockIdx.y;
    const unsigned short* hid = hidb + (size_t)dir * hidds;
    const float* att1 = dir ? a1b : a1f;
    int lane = threadIdx.x & 63, wid = threadIdx.x >> 6;
    int n = blockIdx.x * 4 + wid;
    if (n >= NN) return;
    float p = 0.f;
    if (V == 2) {
        unsigned int u = *(const unsigned int*)(hid + (size_t)n * D + lane * 2);
        p = bf2f(u) * att1[lane * 2] + bf2f(u >> 16) * att1[lane * 2 + 1];
    } else {
        uint2 u = *(const uint2*)(hid + (size_t)n * D + lane * 4);
        p = bf2f(u.x) * att1[lane * 4] + bf2f(u.x >> 16) * att1[lane * 4 + 1]
          + bf2f(u.y) * att1[lane * 4 + 2] + bf2f(u.y >> 16) * att1[lane * 4 + 3];
    }
#pragma unroll
    for (int m = 1; m < 64; m <<= 1) p += __shfl_xor(p, m);
    if (lane == 0) s1[dir * NN + n] = fexp2(p * 1.4426950408889634f);
}

// ---------------- gated-attention context v4: shift-free softmax (es1 precomputed) ----------------
template<int D>
__global__ __launch_bounds__(256) void attn_ctx3_k(const unsigned short* __restrict__ hidb, int hidds,
                                                   const int* __restrict__ adj0, const int* __restrict__ adj1,
                                                   const float* __restrict__ s1,
                                                   unsigned short* __restrict__ ctxb, int ctxds)
{
    constexpr int V = D / 64;
    int dir = blockIdx.y;
    const unsigned short* hid = hidb + (size_t)dir * hidds;
    const int* adj = dir ? adj1 : adj0;
    unsigned short* ctx = ctxb + (size_t)dir * ctxds;
    int lane = threadIdx.x & 63, wid = threadIdx.x >> 6;
    int n = blockIdx.x * 4 + wid;
    if (n >= NN) return;
    int nb[KNB];
    float sc[KNB];
#pragma unroll
    for (int k = 0; k < KNB; ++k) nb[k] = adj[n * KNB + k];
    float s = 0.f;
#pragma unroll
    for (int k = 0; k < KNB; ++k) { sc[k] = (nb[k] < NN) ? s1[dir * NN + nb[k]] : 1.f; s += sc[k]; }
    float inv = frcp(s);
    float accv[V];
#pragma unroll
    for (int j = 0; j < V; ++j) accv[j] = 0.f;
#pragma unroll
    for (int k = 0; k < KNB; ++k) {
        if (nb[k] < NN) {
            if (V == 2) {
                unsigned int u = *(const unsigned int*)(hid + (size_t)nb[k] * D + lane * 2);
                accv[0] += sc[k] * bf2f(u);
                accv[1] += sc[k] * bf2f(u >> 16);
            } else {
                uint2 u = *(const uint2*)(hid + (size_t)nb[k] * D + lane * 4);
                accv[0] += sc[k] * bf2f(u.x);
                accv[1] += sc[k] * bf2f(u.x >> 16);
                accv[2] += sc[k] * bf2f(u.y);
                accv[3] += sc[k] * bf2f(u.y >> 16);
            }
        }
    }
#pragma unroll
    for (int j2 = 0; j2 < V; j2 += 2) {
        unsigned int pk = (unsigned int)f2bf(accv[j2] * inv) | ((unsigned int)f2bf(accv[j2 + 1] * inv) << 16);
        *(unsigned int*)(ctx + (size_t)n * D + lane * V + j2) = pk;
    }
}

// ---------------- graph max pool: two-stage ----------------
__global__ __launch_bounds__(512) void gmax1_k(const float* __restrict__ gh, float* __restrict__ part)
{
    int g = blockIdx.x, ch = blockIdx.y;
    int c = threadIdx.x;
    const float* p = gh + ((size_t)g * 1000 + ch * (1000 / GCH)) * 512 + c;
    float m = -1e30f;
#pragma unroll 5
    for (int i = 0; i < 1000 / GCH; ++i) m = fmaxf(m, p[(size_t)i * 512]);
    part[((size_t)g * GCH + ch) * 512 + c] = m;
}

__global__ __launch_bounds__(512) void gmax2_k(const float* __restrict__ part, float* __restrict__ ge)
{
    int g = blockIdx.x;
    int c = threadIdx.x;
    float m = -1e30f;
#pragma unroll
    for (int i = 0; i < GCH; ++i) m = fmaxf(m, part[((size_t)g * GCH + i) * 512 + c]);
    ge[g * 512 + c] = m;
}

extern "C" void kernel_launch(void* const* d_in, const int* in_sizes, int n_in,
                              void* d_out, int out_size, void* d_ws, size_t ws_size,
                              hipStream_t stream)
{
    const float* embed = (const float*)d_in[0];
    const float* sfWhh = (const float*)d_in[2];
    const float* sfb   = (const float*)d_in[3];
    const float* sbWhh = (const float*)d_in[5];
    const float* sbb   = (const float*)d_in[6];
    const float* ndWih = (const float*)d_in[7];
    const float* ndWhh = (const float*)d_in[8];
    const float* ndb   = (const float*)d_in[9];
    const int* nodefeat = (const int*)d_in[30];
    const int* adj0     = (const int*)d_in[31];
    const int* adj1     = (const int*)d_in[32];
    const int* idxseq   = (const int*)d_in[33];
    const int* lens     = (const int*)d_in[34];
    const int* mlin     = (const int*)d_in[35];

    // ---- workspace layout (f32 offsets), phase-aliased ----
    float* ws = (float*)d_ws;
    unsigned short* warena  = (unsigned short*)ws;                 // [0, 573,440)
    unsigned short* embedbf = (unsigned short*)(ws + 573440);      // [573,440, 2,621,440)
    float* xgf = ws + 2621440;                                     // [2,621,440, 5,898,240)
    float* xgb = ws + 5898240;                                     // [5,898,240, 9,175,040)
    int*   tokrev = (int*)(ws + 9175040);                          // [9,175,040, 9,181,440)
    unsigned short* hbf  = (unsigned short*)(ws + 9181440);        // [9,181,440, 10,781,440)
    unsigned short* hbf2 = (unsigned short*)(ws + 10781440);       // [10,781,440, 12,381,440)
    unsigned short* cbuf = (unsigned short*)(ws + 12381440);       // [12,381,440, 13,987,072) bf16 c
    unsigned short* HA   = (unsigned short*)(ws + 573440);         // phase 3
    unsigned short* HB   = (unsigned short*)(ws + 6973440);        // phase 3
    unsigned short* ctxb = (unsigned short*)(ws + 13987072);       // [13,987,072, 20,387,072)
    float* s1buf = ws + 20387072;                                  // [20,387,072, 20,437,072) es1
    unsigned short* hseq = (unsigned short*)(ws + 20437072);       // [20,437,072, 20,449,872)
    float* cseq = ws + 20449872;                                   // [20,449,872, 20,462,672)
    float* gmaxp = ws + 573440;                                    // phase 4 partials

    float* outf  = (float*)d_out;
    float* gh    = outf;
    float* ge    = outf + 12800000;
    float* omax  = outf + 12812800;
    float* senc  = outf + 12812801;
    float* omask = outf + 14451201;

    // phase 0: preps
    tokrev_k<<<dim3((BB * LL + 255) / 256), dim3(256), 0, stream>>>(idxseq, lens, tokrev);
    embconv_k<<<dim3(VV * 128 / 256), dim3(256), 0, stream>>>(embed, embedbf);
    wprep_k<<<dim3(4480), dim3(256), 0, stream>>>(ndWih, ndWhh,
        (const float*)d_in[12], (const float*)d_in[14], (const float*)d_in[16], (const float*)d_in[18],
        (const float*)d_in[22], (const float*)d_in[24], (const float*)d_in[26], (const float*)d_in[28],
        (const float*)d_in[1], (const float*)d_in[4], sfWhh, sbWhh, warena);

    // phase 1: xg GEMMs (fw+bw in one launch)
    hgemm1_k<<<dim3(50, 8), dim3(256), 0, stream>>>(embedbf, idxseq, tokrev,
        warena + 753664, warena + 819200, sfb, sbb, xgf, xgb);

    // phase 2: node LSTM steps with seq-LSTM chunks riding along
    for (int t = 0; t < NTK; ++t) {
        const unsigned short* hrd = (t & 1) ? hbf2 : hbf;
        unsigned short* hwr = (t & 1) ? hbf : hbf2;   // t=3 writes hbf (final)
        node_seq_k<<<dim3(884), dim3(512), 0, stream>>>(embedbf, nodefeat, hrd,
            warena, ndb, hwr, cbuf, t,
            xgf, xgb, warena + 884736, lens, senc, hseq, cseq);
    }
    finalize_k<<<dim3(1600), dim3(256), 0, stream>>>(idxseq, lens, senc, omask, omax, mlin);

    // phase 3: per layer: es1 + attention gather + fused GEMM launch (BM=64, grid 784)
    for (int l = 0; l < 3; ++l) {
        int D = (l == 0) ? 128 : 256;
        int j = l - 1;
        const unsigned short* curb = (l == 0) ? hbf : (l == 1 ? HA : HB);
        int curds = (l == 0) ? 0 : NN * 256;
        int ctxds = NN * D;
        const float* a1f = (l == 0) ? (const float*)d_in[10] + 128 : (const float*)d_in[11] + (size_t)j * 512 + 256;
        const float* a1b = (l == 0) ? (const float*)d_in[20] + 128 : (const float*)d_in[21] + (size_t)j * 512 + 256;

        if (D == 128) {
            sdot_k<128><<<dim3(NN / 4, 2), dim3(256), 0, stream>>>(curb, curds, a1f, a1b, s1buf);
            attn_ctx3_k<128><<<dim3(NN / 4, 2), dim3(256), 0, stream>>>(curb, curds, adj0, adj1, s1buf, ctxb, ctxds);
        } else {
            sdot_k<256><<<dim3(NN / 4, 2), dim3(256), 0, stream>>>(curb, curds, a1f, a1b, s1buf);
            attn_ctx3_k<256><<<dim3(NN / 4, 2), dim3(256), 0, stream>>>(curb, curds, adj0, adj1, s1buf, ctxb, ctxds);
        }

        const unsigned short* wgb = warena + 131072 + ((l == 0) ? 0 : 16384 + j * 65536);
        const float* bgf = (l == 0) ? (const float*)d_in[13] : (const float*)d_in[15] + (size_t)j * 256;
        const float* bgb = (l == 0) ? (const float*)d_in[23] : (const float*)d_in[25] + (size_t)j * 256;
        const unsigned short* wob = warena + 131072 + ((l == 0) ? 147456 : 180224 + j * 65536);
        int wrs = (l == 0) ? 16384 : 32768;
        const float* bof = (l == 0) ? (const float*)d_in[17] : (const float*)d_in[19] + (size_t)j * 256;
        const float* bob = (l == 0) ? (const float*)d_in[27] : (const float*)d_in[29] + (size_t)j * 256;
        int outds = NN * 256;

        if (l == 0) {
            layer_fused_k<128, 0><<<dim3(784), dim3(512), 0, stream>>>(curb, curds, ctxb, ctxds,
                wgb, 311296, bgf, bgb, wob, 311296, wrs, bof, bob, HA, outds);
        } else if (l == 1) {
            layer_fused_k<256, 0><<<dim3(784), dim3(512), 0, stream>>>(curb, curds, ctxb, ctxds,
                wgb, 311296, bgf, bgb, wob, 311296, wrs, bof, bob, HB, outds);
        } else {
            layer_fused_k<256, 1><<<dim3(784), dim3(512), 0, stream>>>(curb, curds, ctxb, ctxds,
                wgb, 311296, bgf, bgb, wob, 311296, wrs, bof, bob, gh, 0);
        }
    }

    // phase 4: graph embedding max-pool
    gmax1_k<<<dim3(NGRAPH, GCH), dim3(512), 0, stream>>>(gh, gmaxp);
    gmax2_k<<<dim3(NGRAPH), dim3(512), 0, stream>>>(gmaxp, ge);
}

// Round 24
// 555.659 us; speedup vs baseline: 1.3495x; 1.3495x over previous
//
#include <hip/hip_runtime.h>
#include <math.h>

#define NN 25000
#define KNB 16
#define HH 128
#define VV 32000
#define BB 50
#define LL 128
#define NTK 4
#define NGRAPH 25
#define GCH 20

typedef __attribute__((ext_vector_type(8))) short s16x8;
typedef __attribute__((ext_vector_type(4))) float f32x4;
typedef _Float16 h16x2 __attribute__((ext_vector_type(2)));

__device__ __forceinline__ float fexp2(float x) {
#if __has_builtin(__builtin_amdgcn_exp2f)
    return __builtin_amdgcn_exp2f(x);
#else
    return exp2f(x);
#endif
}
__device__ __forceinline__ float frcp(float x) {
#if __has_builtin(__builtin_amdgcn_rcpf)
    return __builtin_amdgcn_rcpf(x);
#else
    return 1.f / x;
#endif
}
__device__ __forceinline__ float fsigm(float x) { return frcp(1.f + fexp2(x * -1.4426950408889634f)); }
__device__ __forceinline__ float ftanh(float x) { return 1.f - 2.f * frcp(1.f + fexp2(x * 2.8853900817779268f)); }

__device__ __forceinline__ unsigned short f2bf(float x) {
    unsigned int u = __float_as_uint(x);
    unsigned int r = (u + 0x7fffu + ((u >> 16) & 1u)) >> 16;
    return (unsigned short)r;
}
__device__ __forceinline__ float bf2f(unsigned int b) {
    return __uint_as_float((b & 0xffffu) << 16);
}

template<int CTRL>
__device__ __forceinline__ float qxor(float x) {
#if __has_builtin(__builtin_amdgcn_mov_dpp)
    return __int_as_float(__builtin_amdgcn_mov_dpp(__float_as_int(x), CTRL, 0xf, 0xf, true));
#else
    int m = (CTRL == 0xB1) ? 1 : (CTRL == 0x4E) ? 2 : 3;
    return __shfl_xor(x, m, 64);
#endif
}

__device__ __forceinline__ float hdot(unsigned int a, unsigned int b, float c) {
#if __has_builtin(__builtin_amdgcn_fdot2)
    return __builtin_amdgcn_fdot2(__builtin_bit_cast(h16x2, a), __builtin_bit_cast(h16x2, b), c, false);
#else
    h16x2 av = __builtin_bit_cast(h16x2, a), bv = __builtin_bit_cast(h16x2, b);
    return c + (float)av[0] * (float)bv[0] + (float)av[1] * (float)bv[1];
#endif
}

// ---------------- embed f32 -> bf16 ----------------
__global__ __launch_bounds__(256) void embconv_k(const float* __restrict__ e,
                                                 unsigned short* __restrict__ o)
{
    int i = blockIdx.x * 256 + threadIdx.x;
    if (i < VV * 128) o[i] = f2bf(e[i]);
}

// ---------------- weight prep (R8 layout) ----------------
__global__ __launch_bounds__(256) void wprep_k(
    const float* __restrict__ ndWih, const float* __restrict__ ndWhh,
    const float* __restrict__ fWg0, const float* __restrict__ fWgr,
    const float* __restrict__ fWo0, const float* __restrict__ fWor,
    const float* __restrict__ bWg0, const float* __restrict__ bWgr,
    const float* __restrict__ bWo0, const float* __restrict__ bWor,
    const float* __restrict__ sfWih, const float* __restrict__ sbWih,
    const float* __restrict__ sfWhh, const float* __restrict__ sbWhh,
    unsigned short* __restrict__ dst)
{
    int idx = blockIdx.x * 256 + threadIdx.x;
    if (idx >= 1146880) return;
    if (idx >= 884736) {
        int r = idx - 884736;
        int d = r >> 17;
        int o = r & 131071;
        int pairIdx = o >> 1, hf = o & 1;
        int k2 = pairIdx >> 9, n = pairIdx & 511;
        int k = k2 * 2 + hf;
        int unit = n >> 2, gate = n & 3;
        const float* W = d ? sbWhh : sfWhh;
        _Float16 hv = (_Float16)W[(gate * 128 + unit) * 128 + k];
        dst[idx] = __builtin_bit_cast(unsigned short, hv);
        return;
    }
    float val;
    if (idx < 131072) {
        int r = idx >> 8, k = idx & 255;
        int unit = r >> 2, gate = r & 3;
        int srow = (gate << 7) + unit;
        val = (k < 128) ? ndWih[srow * 128 + k] : ndWhh[srow * 128 + (k - 128)];
    } else if (idx < 753664) {
        int r = idx - 131072;
        int dir = r / 311296;
        int o = r % 311296;
        const float* Wg0 = dir ? bWg0 : fWg0;
        const float* Wgr = dir ? bWgr : fWgr;
        const float* Wo0 = dir ? bWo0 : fWo0;
        const float* Wor = dir ? bWor : fWor;
        if (o < 16384) {
            int n = o >> 7, k = o & 127;
            val = Wg0[k * 128 + n];
        } else if (o < 147456) {
            int p = o - 16384;
            int j = p >> 16, q = p & 65535;
            int n = q >> 8, k = q & 255;
            val = Wgr[j * 65536 + k * 256 + n];
        } else if (o < 180224) {
            int p = o - 147456;
            int s = p >> 14, q = p & 16383;
            int n = q >> 7, k = q & 127;
            val = Wo0[s * 16384 + k * 128 + n];
        } else {
            int p = o - 180224;
            int js = p >> 15, q = p & 32767;
            int n = q >> 8, k = q & 255;
            val = Wor[js * 32768 + k * 128 + n];
        }
    } else if (idx < 819200) {
        val = sfWih[idx - 753664];
    } else {
        val = sbWih[idx - 819200];
    }
    dst[idx] = f2bf(val);
}

__global__ __launch_bounds__(256) void tokrev_k(const int* __restrict__ idx,
                                                const int* __restrict__ lens,
                                                int* __restrict__ tokrev)
{
    int t = blockIdx.x * 256 + threadIdx.x;
    if (t >= BB * LL) return;
    int b = t / LL, tt = t % LL;
    int r = lens[b] - 1 - tt;
    r = r < 0 ? 0 : (r > LL - 1 ? LL - 1 : r);
    tokrev[t] = idx[b * LL + r];
}

// ---------------- phase-1 dual xg GEMM ----------------
__global__ __launch_bounds__(256) void hgemm1_k(
    const unsigned short* __restrict__ embedbf,
    const int* __restrict__ gidxA, const int* __restrict__ gidxB,
    const unsigned short* __restrict__ WtA, const unsigned short* __restrict__ WtB,
    const float* __restrict__ biasA, const float* __restrict__ biasB,
    float* __restrict__ outA, float* __restrict__ outB)
{
    __shared__ unsigned short Asm[128 * 64];
    __shared__ unsigned short Bsm[128 * 64];
    const int tid = threadIdx.x;
    const int lane = tid & 63, w = tid >> 6;
    const int wm = w >> 1, wn = w & 1;
    const int lane15 = lane & 15, hi = lane >> 4;
    const int y = blockIdx.y;
    const int* gidx = (y < 4) ? gidxA : gidxB;
    const unsigned short* Wt = (y < 4) ? WtA : WtB;
    const float* bias = (y < 4) ? biasA : biasB;
    float* outp = (y < 4) ? outA : outB;
    const int bm0 = blockIdx.x * 128, bn0 = (y & 3) * 128;
    const int M = BB * LL, K = 128;
    f32x4 acc[4][4];
#pragma unroll
    for (int i = 0; i < 4; ++i)
#pragma unroll
        for (int j = 0; j < 4; ++j) acc[i][j] = (f32x4){0.f, 0.f, 0.f, 0.f};

    for (int kt = 0; kt < K; kt += 64) {
#pragma unroll
        for (int r = 0; r < 4; ++r) {
            int id = tid + r * 256;
            int row = id >> 3, cc = id & 7;
            int m = bm0 + row;
            s16x8 v = {0, 0, 0, 0, 0, 0, 0, 0};
            if (m < M) {
                int g = gidx[m];
                v = *(const s16x8*)(embedbf + (size_t)g * 128 + kt + cc * 8);
            }
            int byt = (cc * 16) ^ ((row & 7) << 4);
            *(s16x8*)((char*)Asm + row * 128 + byt) = v;
        }
#pragma unroll
        for (int r = 0; r < 4; ++r) {
            int id = tid + r * 256;
            int row = id >> 3, cc = id & 7;
            s16x8 v = *(const s16x8*)(Wt + (size_t)(bn0 + row) * K + kt + cc * 8);
            int byt = (cc * 16) ^ ((row & 7) << 4);
            *(s16x8*)((char*)Bsm + row * 128 + byt) = v;
        }
        __syncthreads();
#pragma unroll
        for (int ks = 0; ks < 2; ++ks) {
            s16x8 af[4], bf[4];
#pragma unroll
            for (int mi = 0; mi < 4; ++mi) {
                int row = wm * 64 + mi * 16 + lane15;
                int byt = (ks * 64 + (hi * 16)) ^ ((row & 7) << 4);
                af[mi] = *(const s16x8*)((char*)Asm + row * 128 + byt);
            }
#pragma unroll
            for (int ni = 0; ni < 4; ++ni) {
                int row = wn * 64 + ni * 16 + lane15;
                int byt = (ks * 64 + (hi * 16)) ^ ((row & 7) << 4);
                bf[ni] = *(const s16x8*)((char*)Bsm + row * 128 + byt);
            }
#pragma unroll
            for (int mi = 0; mi < 4; ++mi)
#pragma unroll
                for (int ni = 0; ni < 4; ++ni)
                    acc[mi][ni] = __builtin_amdgcn_mfma_f32_16x16x32_bf16(af[mi], bf[ni], acc[mi][ni], 0, 0, 0);
        }
        __syncthreads();
    }
#pragma unroll
    for (int mi = 0; mi < 4; ++mi) {
#pragma unroll
        for (int ni = 0; ni < 4; ++ni) {
            int n = bn0 + wn * 64 + ni * 16 + lane15;
#pragma unroll
            for (int j = 0; j < 4; ++j) {
                int m = bm0 + wm * 64 + mi * 16 + hi * 4 + j;
                if (m < M) {
                    float v = acc[mi][ni][j] + bias[n];
                    int nn = ((n & 127) << 2) | (n >> 7);
                    outp[(size_t)m * 512 + nn] = v;
                }
            }
        }
    }
}

// ---------------- merged node-LSTM step + seq-LSTM chunk ----------------
__global__ __launch_bounds__(512, 4) void node_seq_k(
    const unsigned short* __restrict__ embedbf,
    const int* __restrict__ nodefeat,
    const unsigned short* __restrict__ hrd,
    const unsigned short* __restrict__ nodeW,
    const float* __restrict__ ndb,
    unsigned short* __restrict__ hwr,
    unsigned short* __restrict__ cbuf,
    int step,
    const float* __restrict__ xgf, const float* __restrict__ xgb,
    const unsigned short* __restrict__ wseq,
    const int* __restrict__ lens,
    float* __restrict__ senc,
    unsigned short* __restrict__ hseq, float* __restrict__ cseq)
{
    __shared__ __align__(16) unsigned char smem[32768 + 512];
    const int bid = blockIdx.x;
    const int tid = threadIdx.x;

    if (bid >= 784) {
        int sid = bid - 784;
        int dir = sid >= BB ? 1 : 0;
        int b = dir ? sid - BB : sid;
        int len = lens[b];
        int t0 = step * 32;
        if (t0 >= len) return;
        int t1 = t0 + 32 < len ? t0 + 32 : len;
        const float* xg = (dir ? xgb : xgf) + (size_t)b * LL * 512;
        const unsigned int* wp = (const unsigned int*)(wseq + dir * 131072);
        int q = tid & 3, unit = tid >> 2;
        unsigned int wreg[64];
#pragma unroll
        for (int k2 = 0; k2 < 64; ++k2) wreg[k2] = wp[k2 * 512 + tid];
        unsigned short* hlsq = (unsigned short*)smem;
        float cj = 0.f;
        if (step == 0) {
            if (tid < 128) hlsq[tid] = 0;
        } else {
            if (tid < 128) hlsq[tid] = hseq[sid * 128 + tid];
            if (q == 0) cj = cseq[sid * 128 + unit];
        }
        __syncthreads();
        float xcur = xg[(size_t)t0 * 512 + tid];
        int pb = 0;
        for (int t = t0; t < t1; ++t) {
            float xnext = (t + 1 < t1) ? xg[(size_t)(t + 1) * 512 + tid] : 0.f;
            const uint4* hp = (const uint4*)&hlsq[pb * 128];
            float p0 = 0.f, p1 = 0.f, p2 = 0.f, p3 = 0.f;
#pragma unroll
            for (int i = 0; i < 4; ++i) {
                uint4 h0 = hp[i * 4 + 0], h1 = hp[i * 4 + 1], h2 = hp[i * 4 + 2], h3 = hp[i * 4 + 3];
                const unsigned int* w0 = &wreg[i * 16];
                p0 = hdot(h0.x, w0[0], p0);  p0 = hdot(h0.y, w0[1], p0);
                p0 = hdot(h0.z, w0[2], p0);  p0 = hdot(h0.w, w0[3], p0);
                p1 = hdot(h1.x, w0[4], p1);  p1 = hdot(h1.y, w0[5], p1);
                p1 = hdot(h1.z, w0[6], p1);  p1 = hdot(h1.w, w0[7], p1);
                p2 = hdot(h2.x, w0[8], p2);  p2 = hdot(h2.y, w0[9], p2);
                p2 = hdot(h2.z, w0[10], p2); p2 = hdot(h2.w, w0[11], p2);
                p3 = hdot(h3.x, w0[12], p3); p3 = hdot(h3.y, w0[13], p3);
                p3 = hdot(h3.z, w0[14], p3); p3 = hdot(h3.w, w0[15], p3);
            }
            float accv = xcur + ((p0 + p1) + (p2 + p3));
            float tv = (q == 2) ? ftanh(accv) : fsigm(accv);
            float v1 = __shfl_xor(tv, 1), v2 = __shfl_xor(tv, 2), v3 = __shfl_xor(tv, 3);
            if (q == 0) {
                cj = v1 * cj + tv * v2;
                float hv = v3 * ftanh(cj);
                _Float16 hh = (_Float16)hv;
                hlsq[(pb ^ 1) * 128 + unit] = __builtin_bit_cast(unsigned short, hh);
                int tout = dir ? (len - 1 - t) : t;
                senc[((size_t)b * LL + tout) * 256 + dir * 128 + unit] = hv;
            }
            __syncthreads();
            pb ^= 1;
            xcur = xnext;
        }
        if (q == 0) cseq[sid * 128 + unit] = cj;
        if (tid < 128) hseq[sid * 128 + tid] = hlsq[pb * 128 + tid];
        return;
    }

    unsigned short* Asm = (unsigned short*)smem;
    unsigned short* Bsm = (unsigned short*)(smem + 16384);
    const int lane = tid & 63, w = tid >> 6;
    const int wm = w & 1, wn = w >> 1;
    const int lane15 = lane & 15, hi = lane >> 4, q = lane & 3;
    const int bx = bid % 196, y = bid / 196;
    const int bm0 = bx * 128, bn0 = y * 128;
    const int czero = (step == 0);

    f32x4 acc[4][2];
#pragma unroll
    for (int i = 0; i < 4; ++i)
#pragma unroll
        for (int j = 0; j < 2; ++j) acc[i][j] = (f32x4){0.f, 0.f, 0.f, 0.f};

    for (int kt = 0; kt < 256; kt += 64) {
#pragma unroll
        for (int r = 0; r < 2; ++r) {
            int id = tid + r * 512;
            int row = id >> 3, cc = id & 7;
            int m = bm0 + row;
            s16x8 v = {0, 0, 0, 0, 0, 0, 0, 0};
            if (m < NN) {
                int k0 = kt + cc * 8;
                if (k0 < 128) {
                    int g = nodefeat[m * NTK + step];
                    v = *(const s16x8*)(embedbf + (size_t)g * 128 + k0);
                } else if (!czero) {
                    v = *(const s16x8*)(hrd + (size_t)m * 128 + (k0 - 128));
                }
            }
            int byt = (cc * 16) ^ ((row & 7) << 4);
            *(s16x8*)((char*)Asm + row * 128 + byt) = v;
        }
#pragma unroll
        for (int r = 0; r < 2; ++r) {
            int id = tid + r * 512;
            int row = id >> 3, cc = id & 7;
            s16x8 v = *(const s16x8*)(nodeW + (size_t)(bn0 + row) * 256 + kt + cc * 8);
            int byt = (cc * 16) ^ ((row & 7) << 4);
            *(s16x8*)((char*)Bsm + row * 128 + byt) = v;
        }
        __syncthreads();
#pragma unroll
        for (int ks = 0; ks < 2; ++ks) {
            s16x8 af[4], bf[2];
#pragma unroll
            for (int mi = 0; mi < 4; ++mi) {
                int row = wm * 64 + mi * 16 + lane15;
                int byt = (ks * 64 + (hi * 16)) ^ ((row & 7) << 4);
                af[mi] = *(const s16x8*)((char*)Asm + row * 128 + byt);
            }
#pragma unroll
            for (int ni = 0; ni < 2; ++ni) {
                int row = wn * 32 + ni * 16 + lane15;
                int byt = (ks * 64 + (hi * 16)) ^ ((row & 7) << 4);
                bf[ni] = *(const s16x8*)((char*)Bsm + row * 128 + byt);
            }
#pragma unroll
            for (int mi = 0; mi < 4; ++mi)
#pragma unroll
                for (int ni = 0; ni < 2; ++ni)
                    acc[mi][ni] = __builtin_amdgcn_mfma_f32_16x16x32_bf16(af[mi], bf[ni], acc[mi][ni], 0, 0, 0);
        }
        __syncthreads();
    }
    unsigned short* cb = cbuf + (((size_t)bid * 8 + w) * 64 + lane) * 8;
    float crv[8];
    if (czero) {
#pragma unroll
        for (int i = 0; i < 8; ++i) crv[i] = 0.f;
    } else {
        uint4 w0 = *(const uint4*)cb;
        unsigned int wd[4] = {w0.x, w0.y, w0.z, w0.w};
#pragma unroll
        for (int i = 0; i < 8; ++i) crv[i] = bf2f(wd[i >> 1] >> ((i & 1) * 16));
    }
    const bool qb0 = (lane & 1), qb1 = (lane & 2);
#pragma unroll
    for (int mi = 0; mi < 4; ++mi) {
#pragma unroll
        for (int ni = 0; ni < 2; ++ni) {
            int n = bn0 + wn * 32 + ni * 16 + lane15;
            int unit = n >> 2;
            float bval = ndb[((n & 3) << 7) + unit];
#pragma unroll
            for (int j = 0; j < 4; ++j) {
                float v = acc[mi][ni][j] + bval;
                float tv = (q == 2) ? ftanh(v) : fsigm(v);
                float v1 = qxor<0xB1>(tv), v2 = qxor<0x4E>(tv), v3 = qxor<0x1B>(tv);
                if (q == j) {
                    float gf = qb0 ? (qb1 ? v2 : tv) : (qb1 ? v3 : v1);
                    float gig = qb0 ? (v1 * v3) : (tv * v2);
                    float go = qb0 ? (qb1 ? tv : v2) : (qb1 ? v1 : v3);
                    float cc = gf * crv[mi * 2 + ni] + gig;
                    crv[mi * 2 + ni] = cc;
                    int m = bm0 + wm * 64 + mi * 16 + hi * 4 + j;
                    if (m < NN) hwr[(size_t)m * HH + unit] = f2bf(go * ftanh(cc));
                }
            }
        }
    }
    unsigned int wd[4];
#pragma unroll
    for (int p = 0; p < 4; ++p)
        wd[p] = (unsigned int)f2bf(crv[2 * p]) | ((unsigned int)f2bf(crv[2 * p + 1]) << 16);
    *(uint4*)cb = make_uint4(wd[0], wd[1], wd[2], wd[3]);
}

// ---------------- fused per-layer kernel (BM=64, 2 blocks/CU), 16-row XOR swizzle ----------------
template<int D, int OF32OUT>
__global__ __launch_bounds__(512, 2) void layer_fused_k(
    const unsigned short* __restrict__ cur, int curds,
    const unsigned short* __restrict__ ctx, int ctxds,     // read-only aux
    const unsigned short* __restrict__ wg, int wgds,
    const float* __restrict__ bgf, const float* __restrict__ bgb,
    const unsigned short* __restrict__ wo, int wods, int wrs,
    const float* __restrict__ bof, const float* __restrict__ bob,
    void* __restrict__ outb, int outds)
{
    __shared__ unsigned short As[64 * D];
    __shared__ unsigned short Gs[64 * D];
    __shared__ unsigned short Ws[128 * 64];
    constexpr int gt = D / 128;
    const int tid = threadIdx.x;
    const int lane = tid & 63, w = tid >> 6;
    const int wm = w >> 1, wn = w & 1;
    const int lane15 = lane & 15, hi = lane >> 4;
    const int orig = blockIdx.x;
    const int work = (orig & 7) * 98 + (orig >> 3);
    const int dir = work / 392;
    const int mt = work % 392;
    const int bm0 = mt * 64;
    const unsigned short* curd = cur + (size_t)dir * curds;
    const unsigned short* ctxd = ctx + (size_t)dir * ctxds;
    const float* bg = dir ? bgb : bgf;
    const float* bo = dir ? bob : bof;

    constexpr int CH = D / 8;
#pragma unroll
    for (int r = 0; r < D / 64; ++r) {
        int id = tid + r * 512;
        int row = id / CH, cc = id % CH;
        int m = bm0 + row;
        s16x8 v = {0, 0, 0, 0, 0, 0, 0, 0};
        if (m < NN) v = *(const s16x8*)(curd + (size_t)m * D + cc * 8);
        *(s16x8*)((char*)As + row * (D * 2) + ((cc * 16) ^ ((row & 15) << 4))) = v;
    }
    __syncthreads();

#pragma unroll
    for (int p = 0; p <= gt; ++p) {
        const bool isgate = p < gt;
        const int colBase = isgate ? p * 128 : 0;
        const unsigned short* Wt = isgate ? (wg + (size_t)dir * wgds + (size_t)colBase * D)
                                          : (wo + (size_t)dir * wods);
        f32x4 acc[4];
#pragma unroll
        for (int i = 0; i < 4; ++i) acc[i] = (f32x4){0.f, 0.f, 0.f, 0.f};
        for (int kt = 0; kt < D; kt += 64) {
#pragma unroll
            for (int r = 0; r < 2; ++r) {
                int id = tid + r * 512;
                int row = id >> 3, cc = id & 7;
                s16x8 v = *(const s16x8*)(Wt + (size_t)row * D + kt + cc * 8);
                *(s16x8*)((char*)Ws + row * 128 + ((cc * 16) ^ ((row & 7) << 4))) = v;
            }
            __syncthreads();
#pragma unroll
            for (int ks = 0; ks < 2; ++ks) {
                s16x8 af;
                {
                    int row = wm * 16 + lane15;
                    af = *(const s16x8*)((char*)As + row * (D * 2)
                              + (((kt + ks * 32 + hi * 8) * 2) ^ ((row & 15) << 4)));
                }
#pragma unroll
                for (int ni = 0; ni < 4; ++ni) {
                    int row = wn * 64 + ni * 16 + lane15;
                    s16x8 bf = *(const s16x8*)((char*)Ws + row * 128
                              + (((ks * 32 + hi * 8) * 2) ^ ((row & 7) << 4)));
                    acc[ni] = __builtin_amdgcn_mfma_f32_16x16x32_bf16(af, bf, acc[ni], 0, 0, 0);
                }
            }
            __syncthreads();
        }
#pragma unroll
        for (int ni = 0; ni < 4; ++ni) {
            int ncol = wn * 64 + ni * 16 + lane15;
#pragma unroll
            for (int j = 0; j < 4; ++j) {
                int rr = wm * 16 + hi * 4 + j;
                int m = bm0 + rr;
                if (isgate) {
                    int col = colBase + ncol;
                    float v = acc[ni][j] + bg[col];
                    int ma = (m < NN) ? m : 0;
                    v = fsigm(v) * bf2f(ctxd[(size_t)ma * D + col]);
                    unsigned int pv = f2bf(v);
                    unsigned int po = __shfl_xor((int)pv, 1);
                    if ((lane15 & 1) == 0) {
                        unsigned int word = pv | (po << 16);
                        *(unsigned int*)((char*)Gs + rr * (D * 2) + (((col * 2) & ~3) ^ ((rr & 15) << 4))) = word;
                    }
                } else if (m < NN) {
                    float v = fmaxf(acc[ni][j] + bo[ncol], 0.f);
                    if (OF32OUT) ((float*)outb)[(size_t)m * 512 + dir * 256 + ncol] = v;
                    else ((unsigned short*)outb)[(size_t)dir * outds + (size_t)m * 256 + ncol] = f2bf(v);
                }
            }
        }
    }
    __syncthreads();

    {
        const unsigned short* Wt = wo + (size_t)dir * wods + (size_t)wrs;
        f32x4 acc[4];
#pragma unroll
        for (int i = 0; i < 4; ++i) acc[i] = (f32x4){0.f, 0.f, 0.f, 0.f};
        for (int kt = 0; kt < D; kt += 64) {
#pragma unroll
            for (int r = 0; r < 2; ++r) {
                int id = tid + r * 512;
                int row = id >> 3, cc = id & 7;
                s16x8 v = *(const s16x8*)(Wt + (size_t)row * D + kt + cc * 8);
                *(s16x8*)((char*)Ws + row * 128 + ((cc * 16) ^ ((row & 7) << 4))) = v;
            }
            __syncthreads();
#pragma unroll
            for (int ks = 0; ks < 2; ++ks) {
                s16x8 af;
                {
                    int row = wm * 16 + lane15;
                    af = *(const s16x8*)((char*)Gs + row * (D * 2)
                              + (((kt + ks * 32 + hi * 8) * 2) ^ ((row & 15) << 4)));
                }
#pragma unroll
                for (int ni = 0; ni < 4; ++ni) {
                    int row = wn * 64 + ni * 16 + lane15;
                    s16x8 bf = *(const s16x8*)((char*)Ws + row * 128
                              + (((ks * 32 + hi * 8) * 2) ^ ((row & 7) << 4)));
                    acc[ni] = __builtin_amdgcn_mfma_f32_16x16x32_bf16(af, bf, acc[ni], 0, 0, 0);
                }
            }
            __syncthreads();
        }
#pragma unroll
        for (int ni = 0; ni < 4; ++ni) {
            int ncol = wn * 64 + ni * 16 + lane15;
#pragma unroll
            for (int j = 0; j < 4; ++j) {
                int m = bm0 + wm * 16 + hi * 4 + j;
                if (m < NN) {
                    float v = fmaxf(acc[ni][j] + bo[128 + ncol], 0.f);
                    if (OF32OUT) ((float*)outb)[(size_t)m * 512 + dir * 256 + 128 + ncol] = v;
                    else ((unsigned short*)outb)[(size_t)dir * outds + (size_t)m * 256 + 128 + ncol] = f2bf(v);
                }
            }
        }
    }
}

// ---------------- mask + zero-invalid + max_len ----------------
__global__ __launch_bounds__(256) void finalize_k(const int* __restrict__ idx,
                                                  const int* __restrict__ lens,
                                                  float* __restrict__ senc,
                                                  float* __restrict__ mask,
                                                  float* __restrict__ omax,
                                                  const int* __restrict__ mlin)
{
    int id = blockIdx.x * 256 + threadIdx.x;
    if (id == 0) omax[0] = (float)mlin[0];
    if (id >= BB * LL * 64) return;
    int row = id >> 6, c = id & 63;
    int b = row / LL, tt = row % LL;
    if (c == 0) mask[row] = (idx[row] == 0) ? 1.f : 0.f;
    if (tt >= lens[b]) *(float4*)&senc[(size_t)row * 256 + c * 4] = make_float4(0.f, 0.f, 0.f, 0.f);
}

// ---------------- es1[n] = exp(hid[n,:]·att1) precompute (dirs via grid.y) ----------------
template<int D>
__global__ __launch_bounds__(256) void sdot_k(const unsigned short* __restrict__ hidb, int hidds,
                                              const float* __restrict__ a1f, const float* __restrict__ a1b,
                                              float* __restrict__ s1)
{
    constexpr int V = D / 64;
    int dir = blockIdx.y;
    const unsigned short* hid = hidb + (size_t)dir * hidds;
    const float* att1 = dir ? a1b : a1f;
    int lane = threadIdx.x & 63, wid = threadIdx.x >> 6;
    int n = blockIdx.x * 4 + wid;
    if (n >= NN) return;
    float p = 0.f;
    if (V == 2) {
        unsigned int u = *(const unsigned int*)(hid + (size_t)n * D + lane * 2);
        p = bf2f(u) * att1[lane * 2] + bf2f(u >> 16) * att1[lane * 2 + 1];
    } else {
        uint2 u = *(const uint2*)(hid + (size_t)n * D + lane * 4);
        p = bf2f(u.x) * att1[lane * 4] + bf2f(u.x >> 16) * att1[lane * 4 + 1]
          + bf2f(u.y) * att1[lane * 4 + 2] + bf2f(u.y >> 16) * att1[lane * 4 + 3];
    }
#pragma unroll
    for (int m = 1; m < 64; m <<= 1) p += __shfl_xor(p, m);
    if (lane == 0) s1[dir * NN + n] = fexp2(p * 1.4426950408889634f);
}

// ---------------- gated-attention context v4: shift-free softmax (es1 precomputed) ----------------
template<int D>
__global__ __launch_bounds__(256) void attn_ctx3_k(const unsigned short* __restrict__ hidb, int hidds,
                                                   const int* __restrict__ adj0, const int* __restrict__ adj1,
                                                   const float* __restrict__ s1,
                                                   unsigned short* __restrict__ ctxb, int ctxds)
{
    constexpr int V = D / 64;
    int dir = blockIdx.y;
    const unsigned short* hid = hidb + (size_t)dir * hidds;
    const int* adj = dir ? adj1 : adj0;
    unsigned short* ctx = ctxb + (size_t)dir * ctxds;
    int lane = threadIdx.x & 63, wid = threadIdx.x >> 6;
    int n = blockIdx.x * 4 + wid;
    if (n >= NN) return;
    int nb[KNB];
    float sc[KNB];
#pragma unroll
    for (int k = 0; k < KNB; ++k) nb[k] = adj[n * KNB + k];
    float s = 0.f;
#pragma unroll
    for (int k = 0; k < KNB; ++k) { sc[k] = (nb[k] < NN) ? s1[dir * NN + nb[k]] : 1.f; s += sc[k]; }
    float inv = frcp(s);
    float accv[V];
#pragma unroll
    for (int j = 0; j < V; ++j) accv[j] = 0.f;
#pragma unroll
    for (int k = 0; k < KNB; ++k) {
        if (nb[k] < NN) {
            if (V == 2) {
                unsigned int u = *(const unsigned int*)(hid + (size_t)nb[k] * D + lane * 2);
                accv[0] += sc[k] * bf2f(u);
                accv[1] += sc[k] * bf2f(u >> 16);
            } else {
                uint2 u = *(const uint2*)(hid + (size_t)nb[k] * D + lane * 4);
                accv[0] += sc[k] * bf2f(u.x);
                accv[1] += sc[k] * bf2f(u.x >> 16);
                accv[2] += sc[k] * bf2f(u.y);
                accv[3] += sc[k] * bf2f(u.y >> 16);
            }
        }
    }
#pragma unroll
    for (int j2 = 0; j2 < V; j2 += 2) {
        unsigned int pk = (unsigned int)f2bf(accv[j2] * inv) | ((unsigned int)f2bf(accv[j2 + 1] * inv) << 16);
        *(unsigned int*)(ctx + (size_t)n * D + lane * V + j2) = pk;
    }
}

// ---------------- graph max pool: two-stage ----------------
__global__ __launch_bounds__(512) void gmax1_k(const float* __restrict__ gh, float* __restrict__ part)
{
    int g = blockIdx.x, ch = blockIdx.y;
    int c = threadIdx.x;
    const float* p = gh + ((size_t)g * 1000 + ch * (1000 / GCH)) * 512 + c;
    float m = -1e30f;
#pragma unroll 5
    for (int i = 0; i < 1000 / GCH; ++i) m = fmaxf(m, p[(size_t)i * 512]);
    part[((size_t)g * GCH + ch) * 512 + c] = m;
}

__global__ __launch_bounds__(512) void gmax2_k(const float* __restrict__ part, float* __restrict__ ge)
{
    int g = blockIdx.x;
    int c = threadIdx.x;
    float m = -1e30f;
#pragma unroll
    for (int i = 0; i < GCH; ++i) m = fmaxf(m, part[((size_t)g * GCH + i) * 512 + c]);
    ge[g * 512 + c] = m;
}

extern "C" void kernel_launch(void* const* d_in, const int* in_sizes, int n_in,
                              void* d_out, int out_size, void* d_ws, size_t ws_size,
                              hipStream_t stream)
{
    const float* embed = (const float*)d_in[0];
    const float* sfWhh = (const float*)d_in[2];
    const float* sfb   = (const float*)d_in[3];
    const float* sbWhh = (const float*)d_in[5];
    const float* sbb   = (const float*)d_in[6];
    const float* ndWih = (const float*)d_in[7];
    const float* ndWhh = (const float*)d_in[8];
    const float* ndb   = (const float*)d_in[9];
    const int* nodefeat = (const int*)d_in[30];
    const int* adj0     = (const int*)d_in[31];
    const int* adj1     = (const int*)d_in[32];
    const int* idxseq   = (const int*)d_in[33];
    const int* lens     = (const int*)d_in[34];
    const int* mlin     = (const int*)d_in[35];

    // ---- workspace layout (f32 offsets), phase-aliased ----
    float* ws = (float*)d_ws;
    unsigned short* warena  = (unsigned short*)ws;                 // [0, 573,440)
    unsigned short* embedbf = (unsigned short*)(ws + 573440);      // [573,440, 2,621,440)
    float* xgf = ws + 2621440;                                     // [2,621,440, 5,898,240)
    float* xgb = ws + 5898240;                                     // [5,898,240, 9,175,040)
    int*   tokrev = (int*)(ws + 9175040);                          // [9,175,040, 9,181,440)
    unsigned short* hbf  = (unsigned short*)(ws + 9181440);        // [9,181,440, 10,781,440)
    unsigned short* hbf2 = (unsigned short*)(ws + 10781440);       // [10,781,440, 12,381,440)
    unsigned short* cbuf = (unsigned short*)(ws + 12381440);       // [12,381,440, 13,987,072) bf16 c
    unsigned short* HA   = (unsigned short*)(ws + 573440);         // phase 3
    unsigned short* HB   = (unsigned short*)(ws + 6973440);        // phase 3
    unsigned short* ctxb = (unsigned short*)(ws + 13987072);       // [13,987,072, 20,387,072)
    float* s1buf = ws + 20387072;                                  // [20,387,072, 20,437,072) es1
    unsigned short* hseq = (unsigned short*)(ws + 20437072);       // [20,437,072, 20,449,872)
    float* cseq = ws + 20449872;                                   // [20,449,872, 20,462,672)
    float* gmaxp = ws + 573440;                                    // phase 4 partials

    float* outf  = (float*)d_out;
    float* gh    = outf;
    float* ge    = outf + 12800000;
    float* omax  = outf + 12812800;
    float* senc  = outf + 12812801;
    float* omask = outf + 14451201;

    // phase 0: preps
    tokrev_k<<<dim3((BB * LL + 255) / 256), dim3(256), 0, stream>>>(idxseq, lens, tokrev);
    embconv_k<<<dim3(VV * 128 / 256), dim3(256), 0, stream>>>(embed, embedbf);
    wprep_k<<<dim3(4480), dim3(256), 0, stream>>>(ndWih, ndWhh,
        (const float*)d_in[12], (const float*)d_in[14], (const float*)d_in[16], (const float*)d_in[18],
        (const float*)d_in[22], (const float*)d_in[24], (const float*)d_in[26], (const float*)d_in[28],
        (const float*)d_in[1], (const float*)d_in[4], sfWhh, sbWhh, warena);

    // phase 1: xg GEMMs (fw+bw in one launch)
    hgemm1_k<<<dim3(50, 8), dim3(256), 0, stream>>>(embedbf, idxseq, tokrev,
        warena + 753664, warena + 819200, sfb, sbb, xgf, xgb);

    // phase 2: node LSTM steps with seq-LSTM chunks riding along
    for (int t = 0; t < NTK; ++t) {
        const unsigned short* hrd = (t & 1) ? hbf2 : hbf;
        unsigned short* hwr = (t & 1) ? hbf : hbf2;   // t=3 writes hbf (final)
        node_seq_k<<<dim3(884), dim3(512), 0, stream>>>(embedbf, nodefeat, hrd,
            warena, ndb, hwr, cbuf, t,
            xgf, xgb, warena + 884736, lens, senc, hseq, cseq);
    }
    finalize_k<<<dim3(1600), dim3(256), 0, stream>>>(idxseq, lens, senc, omask, omax, mlin);

    // phase 3: per layer: es1 + attention gather + fused GEMM launch (BM=64, grid 784)
    for (int l = 0; l < 3; ++l) {
        int D = (l == 0) ? 128 : 256;
        int j = l - 1;
        const unsigned short* curb = (l == 0) ? hbf : (l == 1 ? HA : HB);
        int curds = (l == 0) ? 0 : NN * 256;
        int ctxds = NN * D;
        const float* a1f = (l == 0) ? (const float*)d_in[10] + 128 : (const float*)d_in[11] + (size_t)j * 512 + 256;
        const float* a1b = (l == 0) ? (const float*)d_in[20] + 128 : (const float*)d_in[21] + (size_t)j * 512 + 256;

        if (D == 128) {
            sdot_k<128><<<dim3(NN / 4, 2), dim3(256), 0, stream>>>(curb, curds, a1f, a1b, s1buf);
            attn_ctx3_k<128><<<dim3(NN / 4, 2), dim3(256), 0, stream>>>(curb, curds, adj0, adj1, s1buf, ctxb, ctxds);
        } else {
            sdot_k<256><<<dim3(NN / 4, 2), dim3(256), 0, stream>>>(curb, curds, a1f, a1b, s1buf);
            attn_ctx3_k<256><<<dim3(NN / 4, 2), dim3(256), 0, stream>>>(curb, curds, adj0, adj1, s1buf, ctxb, ctxds);
        }

        const unsigned short* wgb = warena + 131072 + ((l == 0) ? 0 : 16384 + j * 65536);
        const float* bgf = (l == 0) ? (const float*)d_in[13] : (const float*)d_in[15] + (size_t)j * 256;
        const float* bgb = (l == 0) ? (const float*)d_in[23] : (const float*)d_in[25] + (size_t)j * 256;
        const unsigned short* wob = warena + 131072 + ((l == 0) ? 147456 : 180224 + j * 65536);
        int wrs = (l == 0) ? 16384 : 32768;
        const float* bof = (l == 0) ? (const float*)d_in[17] : (const float*)d_in[19] + (size_t)j * 256;
        const float* bob = (l == 0) ? (const float*)d_in[27] : (const float*)d_in[29] + (size_t)j * 256;
        int outds = NN * 256;

        if (l == 0) {
            layer_fused_k<128, 0><<<dim3(784), dim3(512), 0, stream>>>(curb, curds, ctxb, ctxds,
                wgb, 311296, bgf, bgb, wob, 311296, wrs, bof, bob, HA, outds);
        } else if (l == 1) {
            layer_fused_k<256, 0><<<dim3(784), dim3(512), 0, stream>>>(curb, curds, ctxb, ctxds,
                wgb, 311296, bgf, bgb, wob, 311296, wrs, bof, bob, HB, outds);
        } else {
            layer_fused_k<256, 1><<<dim3(784), dim3(512), 0, stream>>>(curb, curds, ctxb, ctxds,
                wgb, 311296, bgf, bgb, wob, 311296, wrs, bof, bob, gh, 0);
        }
    }

    // phase 4: graph embedding max-pool
    gmax1_k<<<dim3(NGRAPH, GCH), dim3(512), 0, stream>>>(gh, gmaxp);
    gmax2_k<<<dim3(NGRAPH), dim3(512), 0, stream>>>(gmaxp, ge);
}